// Round 1
// baseline (3662.487 us; speedup 1.0000x reference)
//
#include <hip/hip_runtime.h>
#include <hip/hip_bf16.h>

#define T_STEPS 128
#define B_SZ    1024
#define IN_SZ   47
#define H_SZ    646
#define OUT_SZ  5

// padded geometry
#define XK    64      // xs padded row stride (47 -> 64)
#define HPAD  672     // h region padded (646 -> 672, multiple of 32)
#define K0    736     // layer0 K = 64 + 672
#define K1    1344    // layer1 K = 672 + 672
#define NPAD  704     // output cols padded to 64-multiple (11*64)
#define HROW  1344    // H01 row stride in elements (h0 region | h1 region)

typedef __hip_bfloat16 bf16;
using frag8 = __attribute__((ext_vector_type(8))) short;  // 8 bf16 (4 VGPRs)
using f32x4 = __attribute__((ext_vector_type(4))) float;

// ---------------------------------------------------------------- prep kernels

__global__ void prep_xs(const float* __restrict__ xs, bf16* __restrict__ xs_pad) {
    int idx = blockIdx.x * blockDim.x + threadIdx.x;
    if (idx >= T_STEPS * B_SZ * XK) return;
    int k = idx & (XK - 1);
    int rb = idx >> 6;  // t*B + b
    float v = (k < IN_SZ) ? xs[(size_t)rb * IN_SZ + k] : 0.f;
    xs_pad[idx] = __float2bfloat16(v);
}

__global__ void pack_w0(const float* __restrict__ Wih, const float* __restrict__ Whh,
                        bf16* __restrict__ Wc) {
    int idx = blockIdx.x * blockDim.x + threadIdx.x;
    if (idx >= NPAD * K0) return;
    int j = idx / K0, k = idx % K0;
    float v = 0.f;
    if (j < H_SZ) {
        if (k < IN_SZ)                      v = Wih[(size_t)j * IN_SZ + k];
        else if (k >= XK && k < XK + H_SZ)  v = Whh[(size_t)j * H_SZ + (k - XK)];
    }
    Wc[idx] = __float2bfloat16(v);
}

__global__ void pack_w1(const float* __restrict__ Wih, const float* __restrict__ Whh,
                        bf16* __restrict__ Wc) {
    int idx = blockIdx.x * blockDim.x + threadIdx.x;
    if (idx >= NPAD * K1) return;
    int j = idx / K1, k = idx % K1;
    float v = 0.f;
    if (j < H_SZ) {
        if (k < H_SZ)                           v = Wih[(size_t)j * H_SZ + k];
        else if (k >= HPAD && k < HPAD + H_SZ)  v = Whh[(size_t)j * H_SZ + (k - HPAD)];
    }
    Wc[idx] = __float2bfloat16(v);
}

__global__ void pack_bias(const float* __restrict__ bi, const float* __restrict__ bh,
                          float* __restrict__ b) {
    int j = blockIdx.x * blockDim.x + threadIdx.x;
    if (j >= NPAD) return;
    b[j] = (j < H_SZ) ? (bi[j] + bh[j]) : 0.f;
}

// ---------------------------------------------------------------- step GEMM
// C[row][col] = tanh( sum_k A[row][k] * W[col][k] + bias[col] ), written bf16.
// A[row][k] = k < ksplit ? Alo[row*lda_lo + k] : Ahi[row*lda_hi + k]
// (Ahi is pre-offset by the host so the full-k index is correct.)
// Tile: 64x64 C per block, 256 threads = 4 waves, each wave does a 16-row strip.
__global__ __launch_bounds__(256) void gemm_step(
    const bf16* __restrict__ Alo, int lda_lo,
    const bf16* __restrict__ Ahi, int lda_hi,
    int ksplit, int Ktot,
    const bf16* __restrict__ W,      // [NPAD][Ktot], zero-padded
    const float* __restrict__ bias,  // [NPAD]
    bf16* __restrict__ outp,         // pre-offset to dest region
    int out_stride)
{
    __shared__ unsigned short As[64][40];  // 32 k + 8 pad (bank-conflict break)
    __shared__ unsigned short Bs[64][40];

    const int t    = threadIdx.x;
    const int wave = t >> 6;
    const int lane = t & 63;
    const int row0 = blockIdx.x * 64;
    const int col0 = blockIdx.y * 64;
    const int srow = t >> 2;         // staging row 0..63
    const int skc  = (t & 3) * 8;    // staging k offset within 32-chunk

    const int am = wave * 16 + (lane & 15);  // A fragment row within tile
    const int bn = lane & 15;                // B fragment row offset within 16-tile
    const int fk = (lane >> 4) * 8;          // fragment k offset

    f32x4 acc[4] = {};

    for (int k0 = 0; k0 < Ktot; k0 += 32) {
        const int k = k0 + skc;
        uint4 av, bv;
        if (k < ksplit)
            av = *(const uint4*)(Alo + (size_t)(row0 + srow) * lda_lo + k);
        else
            av = *(const uint4*)(Ahi + (size_t)(row0 + srow) * lda_hi + k);
        bv = *(const uint4*)(W + (size_t)(col0 + srow) * Ktot + k);

        __syncthreads();  // previous iteration's fragment reads complete
        *(uint4*)&As[srow][skc] = av;
        *(uint4*)&Bs[srow][skc] = bv;
        __syncthreads();  // staging visible

        frag8 af  = *(const frag8*)&As[am][fk];
        frag8 bf0 = *(const frag8*)&Bs[ 0 + bn][fk];
        frag8 bf1 = *(const frag8*)&Bs[16 + bn][fk];
        frag8 bf2 = *(const frag8*)&Bs[32 + bn][fk];
        frag8 bf3 = *(const frag8*)&Bs[48 + bn][fk];
        acc[0] = __builtin_amdgcn_mfma_f32_16x16x32_bf16(af, bf0, acc[0], 0, 0, 0);
        acc[1] = __builtin_amdgcn_mfma_f32_16x16x32_bf16(af, bf1, acc[1], 0, 0, 0);
        acc[2] = __builtin_amdgcn_mfma_f32_16x16x32_bf16(af, bf2, acc[2], 0, 0, 0);
        acc[3] = __builtin_amdgcn_mfma_f32_16x16x32_bf16(af, bf3, acc[3], 0, 0, 0);
    }

    // epilogue: C/D layout col = lane&15, row = (lane>>4)*4 + reg
    const int crow = row0 + wave * 16 + (lane >> 4) * 4;
    const int ccol = lane & 15;
    #pragma unroll
    for (int nt = 0; nt < 4; ++nt) {
        int col = col0 + nt * 16 + ccol;
        if (col < H_SZ) {
            float bvs = bias[col];
            #pragma unroll
            for (int i = 0; i < 4; ++i) {
                float x = acc[nt][i] + bvs;
                x = fminf(fmaxf(x, -15.f), 15.f);
                float e = __expf(2.f * x);
                float th = (e - 1.f) / (e + 1.f);
                outp[(size_t)(crow + i) * out_stride + col] = __float2bfloat16(th);
            }
        }
    }
}

// ---------------------------------------------------------------- classifier
// logits[row][o] = sum_k h1[row][k] * Wout[o][k] + bout[o]
__global__ __launch_bounds__(256) void classifier(
    const bf16* __restrict__ h1,   // H01[0] + HPAD (row stride HROW)
    const float* __restrict__ Wout, const float* __restrict__ bout,
    float* __restrict__ out)
{
    const int wave = threadIdx.x >> 6, lane = threadIdx.x & 63;
    const int row = blockIdx.x * 4 + wave;
    float acc[OUT_SZ] = {0.f, 0.f, 0.f, 0.f, 0.f};
    for (int k = lane; k < H_SZ; k += 64) {
        float h = __bfloat162float(h1[(size_t)row * HROW + k]);
        #pragma unroll
        for (int o = 0; o < OUT_SZ; ++o) acc[o] += h * Wout[(size_t)o * H_SZ + k];
    }
    #pragma unroll
    for (int o = 0; o < OUT_SZ; ++o) {
        float v = acc[o];
        #pragma unroll
        for (int off = 32; off; off >>= 1) v += __shfl_down(v, off, 64);
        if (lane == 0) out[(size_t)row * OUT_SZ + o] = v + bout[o];
    }
}

// ---------------------------------------------------------------- launch

extern "C" void kernel_launch(void* const* d_in, const int* in_sizes, int n_in,
                              void* d_out, int out_size, void* d_ws, size_t ws_size,
                              hipStream_t stream) {
    const float* xs   = (const float*)d_in[0];
    const float* Wih0 = (const float*)d_in[1];
    const float* Whh0 = (const float*)d_in[2];
    const float* bih0 = (const float*)d_in[3];
    const float* bhh0 = (const float*)d_in[4];
    const float* Wih1 = (const float*)d_in[5];
    const float* Whh1 = (const float*)d_in[6];
    const float* bih1 = (const float*)d_in[7];
    const float* bhh1 = (const float*)d_in[8];
    const float* Wout = (const float*)d_in[9];
    const float* bout = (const float*)d_in[10];
    float* out = (float*)d_out;

    char* ws = (char*)d_ws;
    size_t off = 0;
    bf16* xs_pad = (bf16*)(ws + off); off += (size_t)T_STEPS * B_SZ * XK * 2;
    bf16* Wc0    = (bf16*)(ws + off); off += (size_t)NPAD * K0 * 2;
    bf16* Wc1    = (bf16*)(ws + off); off += (size_t)NPAD * K1 * 2;
    float* b0    = (float*)(ws + off); off += (size_t)NPAD * 4;
    float* b1    = (float*)(ws + off); off += (size_t)NPAD * 4;
    bf16* H01[2];
    H01[0] = (bf16*)(ws + off); off += (size_t)B_SZ * HROW * 2;
    H01[1] = (bf16*)(ws + off); off += (size_t)B_SZ * HROW * 2;

    // zero both ping-pong activation buffers (h(-1)=0 and padding columns)
    hipMemsetAsync(H01[0], 0, (size_t)B_SZ * HROW * 2 * 2, stream);

    prep_xs <<<(T_STEPS * B_SZ * XK + 255) / 256, 256, 0, stream>>>(xs, xs_pad);
    pack_w0 <<<(NPAD * K0 + 255) / 256, 256, 0, stream>>>(Wih0, Whh0, Wc0);
    pack_w1 <<<(NPAD * K1 + 255) / 256, 256, 0, stream>>>(Wih1, Whh1, Wc1);
    pack_bias<<<(NPAD + 255) / 256, 256, 0, stream>>>(bih0, bhh0, b0);
    pack_bias<<<(NPAD + 255) / 256, 256, 0, stream>>>(bih1, bhh1, b1);

    dim3 grid(B_SZ / 64, NPAD / 64), block(256);
    for (int t = 0; t < T_STEPS; ++t) {
        int p = t & 1;
        // layer 0: A = [x_t (64) | h0 (672)], writes h0_new into H01[1-p] cols 0..645
        gemm_step<<<grid, block, 0, stream>>>(
            xs_pad + (size_t)t * B_SZ * XK, XK,
            H01[p] - XK, HROW,
            XK, K0, Wc0, b0,
            H01[1 - p], HROW);
        // layer 1: A = [h0_new (672, from H01[1-p]) | h1 (672, from H01[p])],
        // writes h1_new into H01[1-p] cols 672..1317
        gemm_step<<<grid, block, 0, stream>>>(
            H01[1 - p], HROW,
            H01[p], HROW,
            HPAD, K1, Wc1, b1,
            H01[1 - p] + HPAD, HROW);
    }
    // t=127 has p=1, final state lives in H01[0]
    classifier<<<B_SZ / 4, 256, 0, stream>>>(H01[0] + HPAD, Wout, bout, out);
}

// Round 2
// 2445.822 us; speedup vs baseline: 1.4974x; 1.4974x over previous
//
#include <hip/hip_runtime.h>
#include <hip/hip_bf16.h>

#define T_STEPS 128
#define B_SZ    1024
#define IN_SZ   47
#define H_SZ    646
#define OUT_SZ  5

// padded geometry
#define XK    96      // xs padded row stride (47 -> 96) so K0 = 768 = 12*64
#define HPAD  672     // h region padded (646 -> 672, multiple of 32)
#define K0    768     // layer0 K = 96 + 672  (divisible by 64)
#define K1    1344    // layer1 K = 672 + 672 (divisible by 64)
#define NPAD  704     // output cols padded to 64-multiple (11*64)
#define HROW  1344    // H01 row stride in elements (h0 region | h1 region)

typedef __hip_bfloat16 bf16;
using frag8 = __attribute__((ext_vector_type(8))) short;  // 8 bf16 (4 VGPRs)
using f32x4 = __attribute__((ext_vector_type(4))) float;

// ---------------------------------------------------------------- prep kernels

__global__ void prep_xs(const float* __restrict__ xs, bf16* __restrict__ xs_pad) {
    int idx = blockIdx.x * blockDim.x + threadIdx.x;
    if (idx >= T_STEPS * B_SZ * XK) return;
    int k = idx % XK;
    int rb = idx / XK;  // t*B + b
    float v = (k < IN_SZ) ? xs[(size_t)rb * IN_SZ + k] : 0.f;
    xs_pad[idx] = __float2bfloat16(v);
}

__global__ void pack_w0(const float* __restrict__ Wih, const float* __restrict__ Whh,
                        bf16* __restrict__ Wc) {
    int idx = blockIdx.x * blockDim.x + threadIdx.x;
    if (idx >= NPAD * K0) return;
    int j = idx / K0, k = idx % K0;
    float v = 0.f;
    if (j < H_SZ) {
        if (k < IN_SZ)                      v = Wih[(size_t)j * IN_SZ + k];
        else if (k >= XK && k < XK + H_SZ)  v = Whh[(size_t)j * H_SZ + (k - XK)];
    }
    Wc[idx] = __float2bfloat16(v);
}

__global__ void pack_w1(const float* __restrict__ Wih, const float* __restrict__ Whh,
                        bf16* __restrict__ Wc) {
    int idx = blockIdx.x * blockDim.x + threadIdx.x;
    if (idx >= NPAD * K1) return;
    int j = idx / K1, k = idx % K1;
    float v = 0.f;
    if (j < H_SZ) {
        if (k < H_SZ)                           v = Wih[(size_t)j * H_SZ + k];
        else if (k >= HPAD && k < HPAD + H_SZ)  v = Whh[(size_t)j * H_SZ + (k - HPAD)];
    }
    Wc[idx] = __float2bfloat16(v);
}

__global__ void pack_bias(const float* __restrict__ bi, const float* __restrict__ bh,
                          float* __restrict__ b) {
    int j = blockIdx.x * blockDim.x + threadIdx.x;
    if (j >= NPAD) return;
    b[j] = (j < H_SZ) ? (bi[j] + bh[j]) : 0.f;
}

// ---------------------------------------------------------------- step GEMM body
// C[row][col] = tanh( sum_k A[row][k] * W[col][k] + bias[col] ), written bf16.
// A[row][k] = k < ksplit ? Alo[row*lda_lo + k] : Ahi[row*lda_hi + k]
// (Ahi pre-offset by the host so the full-k index lands correctly.)
struct GArgs {
    const bf16* Alo; const bf16* Ahi;
    int lda_lo, lda_hi, ksplit, Ktot;
    const bf16* W;      // [NPAD][Ktot], zero-padded
    const float* bias;  // [NPAD]
    bf16* outp;         // pre-offset to dest region
    int out_stride;
};

typedef unsigned short ush;

__device__ __forceinline__ void gemm_dev(const GArgs g, int bid,
                                         ush (*As)[72], ush (*Bs)[72]) {
    const int t    = threadIdx.x;
    const int wave = t >> 6;
    const int lane = t & 63;
    const int row0 = (bid & 15) * 64;   // 16 row tiles (B=1024)
    const int col0 = (bid >> 4) * 64;   // 11 col tiles (NPAD=704)
    const int srow = t >> 2;            // staging row 0..63
    const int skc  = (t & 3) * 16;      // staging k offset within 64-chunk

    const int am = wave * 16 + (lane & 15);  // A fragment row within tile
    const int bn = lane & 15;                // B fragment row offset within 16-tile
    const int fk = (lane >> 4) * 8;          // fragment k offset

    f32x4 acc[4] = {};

    const size_t arow_lo = (size_t)(row0 + srow) * g.lda_lo;
    const size_t arow_hi = (size_t)(row0 + srow) * g.lda_hi;
    const bf16* wrow = g.W + (size_t)(col0 + srow) * g.Ktot;

    for (int k0 = 0; k0 < g.Ktot; k0 += 64) {
        uint4 av0, av1, bv0, bv1;
        {
            int ka = k0 + skc, kb = ka + 8;
            av0 = (ka < g.ksplit) ? *(const uint4*)(g.Alo + arow_lo + ka)
                                  : *(const uint4*)(g.Ahi + arow_hi + ka);
            av1 = (kb < g.ksplit) ? *(const uint4*)(g.Alo + arow_lo + kb)
                                  : *(const uint4*)(g.Ahi + arow_hi + kb);
            bv0 = *(const uint4*)(wrow + ka);
            bv1 = *(const uint4*)(wrow + kb);
        }
        __syncthreads();  // previous iteration's fragment reads complete
        *(uint4*)&As[srow][skc]     = av0;
        *(uint4*)&As[srow][skc + 8] = av1;
        *(uint4*)&Bs[srow][skc]     = bv0;
        *(uint4*)&Bs[srow][skc + 8] = bv1;
        __syncthreads();  // staging visible

        #pragma unroll
        for (int h = 0; h < 2; ++h) {
            const int o = h * 32 + fk;
            frag8 af  = *(const frag8*)&As[am][o];
            acc[0] = __builtin_amdgcn_mfma_f32_16x16x32_bf16(af, *(const frag8*)&Bs[ 0 + bn][o], acc[0], 0, 0, 0);
            acc[1] = __builtin_amdgcn_mfma_f32_16x16x32_bf16(af, *(const frag8*)&Bs[16 + bn][o], acc[1], 0, 0, 0);
            acc[2] = __builtin_amdgcn_mfma_f32_16x16x32_bf16(af, *(const frag8*)&Bs[32 + bn][o], acc[2], 0, 0, 0);
            acc[3] = __builtin_amdgcn_mfma_f32_16x16x32_bf16(af, *(const frag8*)&Bs[48 + bn][o], acc[3], 0, 0, 0);
        }
    }

    // epilogue: C/D layout col = lane&15, row = (lane>>4)*4 + reg
    const int crow = row0 + wave * 16 + (lane >> 4) * 4;
    const int ccol = lane & 15;
    #pragma unroll
    for (int nt = 0; nt < 4; ++nt) {
        int col = col0 + nt * 16 + ccol;
        if (col < H_SZ) {
            float bvs = g.bias[col];
            #pragma unroll
            for (int i = 0; i < 4; ++i) {
                float x = acc[nt][i] + bvs;
                x = fminf(fmaxf(x, -15.f), 15.f);
                float e = __expf(2.f * x);
                float th = (e - 1.f) / (e + 1.f);
                g.outp[(size_t)(crow + i) * g.out_stride + col] = __float2bfloat16(th);
            }
        }
    }
}

// blocks [0,nA) run config a (tile id = bid), blocks [nA,..) run config b.
__global__ __launch_bounds__(256) void step_kernel(GArgs a, GArgs b, int nA) {
    __shared__ ush As[64][72];
    __shared__ ush Bs[64][72];
    const int bid = blockIdx.x;
    if (bid < nA) gemm_dev(a, bid, As, Bs);
    else          gemm_dev(b, bid - nA, As, Bs);
}

// ---------------------------------------------------------------- classifier
__global__ __launch_bounds__(256) void classifier(
    const bf16* __restrict__ h1,   // final h1, row stride HROW
    const float* __restrict__ Wout, const float* __restrict__ bout,
    float* __restrict__ out)
{
    const int wave = threadIdx.x >> 6, lane = threadIdx.x & 63;
    const int row = blockIdx.x * 4 + wave;
    float acc[OUT_SZ] = {0.f, 0.f, 0.f, 0.f, 0.f};
    for (int k = lane; k < H_SZ; k += 64) {
        float h = __bfloat162float(h1[(size_t)row * HROW + k]);
        #pragma unroll
        for (int o = 0; o < OUT_SZ; ++o) acc[o] += h * Wout[(size_t)o * H_SZ + k];
    }
    #pragma unroll
    for (int o = 0; o < OUT_SZ; ++o) {
        float v = acc[o];
        #pragma unroll
        for (int off = 32; off; off >>= 1) v += __shfl_down(v, off, 64);
        if (lane == 0) out[(size_t)row * OUT_SZ + o] = v + bout[o];
    }
}

// ---------------------------------------------------------------- launch

extern "C" void kernel_launch(void* const* d_in, const int* in_sizes, int n_in,
                              void* d_out, int out_size, void* d_ws, size_t ws_size,
                              hipStream_t stream) {
    const float* xs   = (const float*)d_in[0];
    const float* Wih0 = (const float*)d_in[1];
    const float* Whh0 = (const float*)d_in[2];
    const float* bih0 = (const float*)d_in[3];
    const float* bhh0 = (const float*)d_in[4];
    const float* Wih1 = (const float*)d_in[5];
    const float* Whh1 = (const float*)d_in[6];
    const float* bih1 = (const float*)d_in[7];
    const float* bhh1 = (const float*)d_in[8];
    const float* Wout = (const float*)d_in[9];
    const float* bout = (const float*)d_in[10];
    float* out = (float*)d_out;

    char* ws = (char*)d_ws;
    size_t off = 0;
    bf16* xs_pad = (bf16*)(ws + off); off += (size_t)T_STEPS * B_SZ * XK * 2;
    bf16* Wc0    = (bf16*)(ws + off); off += (size_t)NPAD * K0 * 2;
    bf16* Wc1    = (bf16*)(ws + off); off += (size_t)NPAD * K1 * 2;
    float* b0    = (float*)(ws + off); off += (size_t)NPAD * 4;
    float* b1    = (float*)(ws + off); off += (size_t)NPAD * 4;
    bf16* H01[2];
    H01[0] = (bf16*)(ws + off); off += (size_t)B_SZ * HROW * 2;
    H01[1] = (bf16*)(ws + off); off += (size_t)B_SZ * HROW * 2;

    // zero both ping-pong activation buffers (h(-1)=0 and padding columns)
    hipMemsetAsync(H01[0], 0, (size_t)B_SZ * HROW * 2 * 2, stream);

    prep_xs <<<(T_STEPS * B_SZ * XK + 255) / 256, 256, 0, stream>>>(xs, xs_pad);
    pack_w0 <<<(NPAD * K0 + 255) / 256, 256, 0, stream>>>(Wih0, Whh0, Wc0);
    pack_w1 <<<(NPAD * K1 + 255) / 256, 256, 0, stream>>>(Wih1, Whh1, Wc1);
    pack_bias<<<(NPAD + 255) / 256, 256, 0, stream>>>(bih0, bhh0, b0);
    pack_bias<<<(NPAD + 255) / 256, 256, 0, stream>>>(bih1, bhh1, b1);

    auto make_l0 = [&](int t) {
        int p = t & 1;
        GArgs g;
        g.Alo = xs_pad + (size_t)t * B_SZ * XK; g.lda_lo = XK;
        g.Ahi = H01[p] - XK;                    g.lda_hi = HROW;
        g.ksplit = XK; g.Ktot = K0;
        g.W = Wc0; g.bias = b0;
        g.outp = H01[1 - p]; g.out_stride = HROW;
        return g;
    };
    auto make_l1 = [&](int s) {
        int ps = s & 1;
        GArgs g;
        g.Alo = H01[1 - ps]; g.lda_lo = HROW;
        g.Ahi = H01[ps];     g.lda_hi = HROW;
        g.ksplit = HPAD; g.Ktot = K1;
        g.W = Wc1; g.bias = b1;
        g.outp = H01[1 - ps] + HPAD; g.out_stride = HROW;
        return g;
    };

    const int NB = (B_SZ / 64) * (NPAD / 64);  // 176 blocks per sub-GEMM

    // t = 0: layer0 only
    {
        GArgs a0 = make_l0(0);
        step_kernel<<<NB, 256, 0, stream>>>(a0, a0, NB);
    }
    // t = 1..127: L1(t-1) (longer, scheduled first) || L0(t)
    for (int t = 1; t < T_STEPS; ++t) {
        GArgs aL1 = make_l1(t - 1);
        GArgs aL0 = make_l0(t);
        step_kernel<<<2 * NB, 256, 0, stream>>>(aL1, aL0, NB);
    }
    // final layer1
    {
        GArgs aF = make_l1(T_STEPS - 1);
        step_kernel<<<NB, 256, 0, stream>>>(aF, aF, NB);
    }
    // final h1 lives in H01[0] + HPAD (L1(127): ps=1 -> writes H01[0])
    classifier<<<B_SZ / 4, 256, 0, stream>>>(H01[0] + HPAD, Wout, bout, out);
}

// Round 3
// 1975.579 us; speedup vs baseline: 1.8539x; 1.2380x over previous
//
#include <hip/hip_runtime.h>
#include <hip/hip_bf16.h>

#define T_STEPS 128
#define B_SZ    1024
#define IN_SZ   47
#define H_SZ    646
#define OUT_SZ  5

#define XK    96      // xs padded row stride (47 -> 96)
#define K0    768     // layer0 K = 96 + 672
#define K1    1344    // layer1 K = 672 + 672 (also the state-slab row stride)
#define N0PAD 704     // L0 cols padded (11 * 64)
#define N1PAD 672     // L1 cols padded (21 * 32)
#define RING  17      // state ring slots per row-group (fresh-address coherence)
#define SLAB  172032  // 128 rows * 1344 cols, elements per rg slab
#define PH    129     // phases: p=0..128

typedef __hip_bfloat16 bf16;
typedef unsigned short ush;
using frag8 = __attribute__((ext_vector_type(8))) short;  // 8 bf16
using f32x4 = __attribute__((ext_vector_type(4))) float;

// ---------------------------------------------------------------- prep kernels

__global__ void prep_xs(const float* __restrict__ xs, bf16* __restrict__ xs_pad) {
    int idx = blockIdx.x * blockDim.x + threadIdx.x;
    if (idx >= T_STEPS * B_SZ * XK) return;
    int k = idx % XK;
    int rb = idx / XK;
    float v = (k < IN_SZ) ? xs[(size_t)rb * IN_SZ + k] : 0.f;
    xs_pad[idx] = __float2bfloat16(v);
}

__global__ void pack_w0(const float* __restrict__ Wih, const float* __restrict__ Whh,
                        bf16* __restrict__ Wc) {
    int idx = blockIdx.x * blockDim.x + threadIdx.x;
    if (idx >= N0PAD * K0) return;
    int j = idx / K0, k = idx % K0;
    float v = 0.f;
    if (j < H_SZ) {
        if (k < IN_SZ)                      v = Wih[(size_t)j * IN_SZ + k];
        else if (k >= XK && k < XK + H_SZ)  v = Whh[(size_t)j * H_SZ + (k - XK)];
    }
    Wc[idx] = __float2bfloat16(v);
}

__global__ void pack_w1(const float* __restrict__ Wih, const float* __restrict__ Whh,
                        bf16* __restrict__ Wc) {
    int idx = blockIdx.x * blockDim.x + threadIdx.x;
    if (idx >= N1PAD * K1) return;
    int j = idx / K1, k = idx % K1;
    float v = 0.f;
    if (j < H_SZ) {
        if (k < H_SZ)                          v = Wih[(size_t)j * H_SZ + k];
        else if (k >= 672 && k < 672 + H_SZ)   v = Whh[(size_t)j * H_SZ + (k - 672)];
    }
    Wc[idx] = __float2bfloat16(v);
}

__global__ void pack_bias(const float* __restrict__ bi, const float* __restrict__ bh,
                          float* __restrict__ b, int n) {
    int j = blockIdx.x * blockDim.x + threadIdx.x;
    if (j >= n) return;
    b[j] = (j < H_SZ) ? (bi[j] + bh[j]) : 0.f;
}

// ---------------------------------------------------------------- persistent RNN
// 256 blocks: bid&7 = row-group (128 rows), bid>>3 = role/col-block:
//   c8 in [0,11): L0, 64-col tile, W0 slice (96 KB) pinned in LDS
//   c8 in [11,32): L1, 32-col tile, W1 slice (84 KB) pinned in LDS
// Phase p: L0 computes h0(p) (p<128); L1 computes h1(p-1) (p>=1).
// State lives in a per-rg ring of RING fresh slabs; producers store with
// agent-scope (write-through) stores, consumers use cached loads + one
// agent-acquire fence per ring wrap. Row-group sync via flag counters.

__device__ __forceinline__ void tanh_store(ush* dst, float x) {
    x = fminf(fmaxf(x, -15.f), 15.f);
    float e = __expf(2.f * x);
    bf16 hb = __float2bfloat16((e - 1.f) / (e + 1.f));
    __hip_atomic_store(dst, *(ush*)&hb, __ATOMIC_RELAXED, __HIP_MEMORY_SCOPE_AGENT);
}

__global__ __launch_bounds__(256, 1) void persist(
    const bf16* __restrict__ xs_pad, const bf16* __restrict__ Wc0,
    const bf16* __restrict__ Wc1, const float* __restrict__ b0,
    const float* __restrict__ b1, bf16* __restrict__ Sring,
    int* __restrict__ flags)
{
    extern __shared__ ush Wlds[];
    const int bid  = blockIdx.x;
    const int rg   = bid & 7;
    const int c8   = bid >> 3;
    const bool isL0 = (c8 < 11);
    const int wave = threadIdx.x >> 6;
    const int lane = threadIdx.x & 63;
    const int q8   = (lane >> 4) * 8;   // fragment k offset (elements)
    const int l15  = lane & 15;

    // ---- stage W slice into LDS in fragment order (once) ----
    if (isL0) {
        const int col0 = c8 * 64;
        for (int g = wave; g < 96; g += 4) {          // g = kc*4 + ct
            int kc = g >> 2, ct = g & 3;
            const bf16* src = Wc0 + (size_t)(col0 + ct*16 + l15) * K0 + kc*32 + q8;
            *(uint4*)&Wlds[g*512 + lane*8] = *(const uint4*)src;
        }
    } else {
        const int col0 = (c8 - 11) * 32;
        for (int g = wave; g < 84; g += 4) {          // g = kc*2 + ct
            int kc = g >> 1, ct = g & 1;
            const bf16* src = Wc1 + (size_t)(col0 + ct*16 + l15) * K1 + kc*32 + q8;
            *(uint4*)&Wlds[g*512 + lane*8] = *(const uint4*)src;
        }
    }
    __syncthreads();

    // hoisted per-thread constants
    float bias[4];
    int col0;
    if (isL0) {
        col0 = c8 * 64;
        #pragma unroll
        for (int ct = 0; ct < 4; ++ct) bias[ct] = b0[col0 + ct*16 + l15];
    } else {
        col0 = (c8 - 11) * 32;
        #pragma unroll
        for (int ct = 0; ct < 2; ++ct) bias[ct] = b1[col0 + ct*16 + l15];
    }
    const int loc0 = wave * 32 + l15;   // local row, r=0 frag
    const int loc1 = loc0 + 16;         // local row, r=1 frag
    bf16* const ringbase = Sring + (size_t)rg * RING * SLAB;
    int*  const flagbase = flags + rg * PH;

    for (int p = 0; p <= 128; ++p) {
        if (p > 0) {
            if (threadIdx.x == 0) {
                while (__hip_atomic_load(&flagbase[p-1], __ATOMIC_RELAXED,
                                         __HIP_MEMORY_SCOPE_AGENT) < 32)
                    __builtin_amdgcn_s_sleep(2);
            }
            __syncthreads();
            // ring wrap: recycled addresses may be stale in L1/L2 -> invalidate
            if (p >= RING + 1 && (p - 1) % RING == 0)
                __builtin_amdgcn_fence(__ATOMIC_ACQUIRE, "agent");
        }
        const bf16* rsl = ringbase + (size_t)((p + RING - 1) % RING) * SLAB;
        bf16*       wsl = ringbase + (size_t)(p % RING) * SLAB;
        const bool active = isL0 ? (p < 128) : (p >= 1);

        if (active) {
            if (isL0) {
                // A = [x_t(96) | h0(t-1)(672)], C = h0(t) -> slab cols [0,672)
                const bf16* xsb = xs_pad + ((size_t)p * B_SZ + rg*128) * XK;
                const bf16* x0  = xsb + (size_t)loc0 * XK + q8;
                const bf16* x1  = xsb + (size_t)loc1 * XK + q8;
                const bf16* h0p = rsl + (size_t)loc0 * K1 + q8;
                const bf16* h1p = rsl + (size_t)loc1 * K1 + q8;
                f32x4 acc[2][4] = {};
                auto ldA = [&](int kc, int r) -> uint4 {
                    if (kc < 3) return *(const uint4*)((r ? x1 : x0) + kc*32);
                    return *(const uint4*)((r ? h1p : h0p) + (kc-3)*32);
                };
                uint4 ac[2], an[2];
                ac[0] = ldA(0,0); ac[1] = ldA(0,1);
                an[0] = ldA(1,0); an[1] = ldA(1,1);
                #pragma unroll
                for (int kc = 0; kc < 24; ++kc) {
                    uint4 a2[2];
                    if (kc + 2 < 24) { a2[0] = ldA(kc+2,0); a2[1] = ldA(kc+2,1); }
                    else             { a2[0] = ac[0];       a2[1] = ac[1]; }
                    #pragma unroll
                    for (int ct = 0; ct < 4; ++ct) {
                        frag8 wf = *(const frag8*)&Wlds[(kc*4+ct)*512 + lane*8];
                        acc[0][ct] = __builtin_amdgcn_mfma_f32_16x16x32_bf16(
                            *(const frag8*)&ac[0], wf, acc[0][ct], 0,0,0);
                        acc[1][ct] = __builtin_amdgcn_mfma_f32_16x16x32_bf16(
                            *(const frag8*)&ac[1], wf, acc[1][ct], 0,0,0);
                    }
                    ac[0]=an[0]; ac[1]=an[1]; an[0]=a2[0]; an[1]=a2[1];
                }
                #pragma unroll
                for (int r = 0; r < 2; ++r) {
                    const int rbase = wave*32 + r*16 + (lane>>4)*4;
                    #pragma unroll
                    for (int ct = 0; ct < 4; ++ct) {
                        const int col = col0 + ct*16 + l15;
                        if (col < H_SZ) {
                            #pragma unroll
                            for (int i = 0; i < 4; ++i)
                                tanh_store((ush*)(wsl + (size_t)(rbase+i)*K1 + col),
                                           acc[r][ct][i] + bias[ct]);
                        }
                    }
                }
            } else {
                // A = slab row [h0(t-1) | h1(t-2)] (contiguous K=1344)
                // C = h1(t-1) -> slab cols [672, 1344)
                const bf16* a0 = rsl + (size_t)loc0 * K1 + q8;
                const bf16* a1 = rsl + (size_t)loc1 * K1 + q8;
                f32x4 acc[2][2] = {};
                uint4 ac[2], an[2];
                ac[0] = *(const uint4*)(a0);      ac[1] = *(const uint4*)(a1);
                an[0] = *(const uint4*)(a0 + 32); an[1] = *(const uint4*)(a1 + 32);
                #pragma unroll
                for (int kc = 0; kc < 42; ++kc) {
                    uint4 a2[2];
                    if (kc + 2 < 42) { a2[0] = *(const uint4*)(a0 + (kc+2)*32);
                                       a2[1] = *(const uint4*)(a1 + (kc+2)*32); }
                    else             { a2[0] = ac[0]; a2[1] = ac[1]; }
                    #pragma unroll
                    for (int ct = 0; ct < 2; ++ct) {
                        frag8 wf = *(const frag8*)&Wlds[(kc*2+ct)*512 + lane*8];
                        acc[0][ct] = __builtin_amdgcn_mfma_f32_16x16x32_bf16(
                            *(const frag8*)&ac[0], wf, acc[0][ct], 0,0,0);
                        acc[1][ct] = __builtin_amdgcn_mfma_f32_16x16x32_bf16(
                            *(const frag8*)&ac[1], wf, acc[1][ct], 0,0,0);
                    }
                    ac[0]=an[0]; ac[1]=an[1]; an[0]=a2[0]; an[1]=a2[1];
                }
                #pragma unroll
                for (int r = 0; r < 2; ++r) {
                    const int rbase = wave*32 + r*16 + (lane>>4)*4;
                    #pragma unroll
                    for (int ct = 0; ct < 2; ++ct) {
                        const int col = col0 + ct*16 + l15;
                        if (col < H_SZ) {
                            #pragma unroll
                            for (int i = 0; i < 4; ++i)
                                tanh_store((ush*)(wsl + (size_t)(rbase+i)*K1 + 672 + col),
                                           acc[r][ct][i] + bias[ct]);
                        }
                    }
                }
            }
        }
        __syncthreads();   // all waves' stores drained (vmcnt 0 before barrier)
        if (threadIdx.x == 0)
            __hip_atomic_fetch_add(&flagbase[p], 1, __ATOMIC_RELAXED,
                                   __HIP_MEMORY_SCOPE_AGENT);
    }
}

// ---------------------------------------------------------------- classifier
__global__ __launch_bounds__(256) void classifier(
    const bf16* __restrict__ Sring, const float* __restrict__ Wout,
    const float* __restrict__ bout, float* __restrict__ out)
{
    const int wave = threadIdx.x >> 6, lane = threadIdx.x & 63;
    const int row = blockIdx.x * 4 + wave;
    const int rg = row >> 7, loc = row & 127;
    const bf16* h1 = Sring + ((size_t)rg * RING + (128 % RING)) * SLAB
                     + (size_t)loc * K1 + 672;
    float acc[OUT_SZ] = {0.f, 0.f, 0.f, 0.f, 0.f};
    for (int k = lane; k < H_SZ; k += 64) {
        float h = __bfloat162float(h1[k]);
        #pragma unroll
        for (int o = 0; o < OUT_SZ; ++o) acc[o] += h * Wout[(size_t)o * H_SZ + k];
    }
    #pragma unroll
    for (int o = 0; o < OUT_SZ; ++o) {
        float v = acc[o];
        #pragma unroll
        for (int off = 32; off; off >>= 1) v += __shfl_down(v, off, 64);
        if (lane == 0) out[(size_t)row * OUT_SZ + o] = v + bout[o];
    }
}

// ---------------------------------------------------------------- launch

extern "C" void kernel_launch(void* const* d_in, const int* in_sizes, int n_in,
                              void* d_out, int out_size, void* d_ws, size_t ws_size,
                              hipStream_t stream) {
    const float* xs   = (const float*)d_in[0];
    const float* Wih0 = (const float*)d_in[1];
    const float* Whh0 = (const float*)d_in[2];
    const float* bih0 = (const float*)d_in[3];
    const float* bhh0 = (const float*)d_in[4];
    const float* Wih1 = (const float*)d_in[5];
    const float* Whh1 = (const float*)d_in[6];
    const float* bih1 = (const float*)d_in[7];
    const float* bhh1 = (const float*)d_in[8];
    const float* Wout = (const float*)d_in[9];
    const float* bout = (const float*)d_in[10];
    float* out = (float*)d_out;

    char* ws = (char*)d_ws;
    size_t off = 0;
    bf16* xs_pad = (bf16*)(ws + off); off += (size_t)T_STEPS * B_SZ * XK * 2;
    bf16* Wc0    = (bf16*)(ws + off); off += (size_t)N0PAD * K0 * 2;
    bf16* Wc1    = (bf16*)(ws + off); off += (size_t)N1PAD * K1 * 2;
    float* b0    = (float*)(ws + off); off += (size_t)N0PAD * 4;
    float* b1    = (float*)(ws + off); off += (size_t)N1PAD * 4;
    bf16* Sring  = (bf16*)(ws + off); off += (size_t)8 * RING * SLAB * 2;
    int*  flags  = (int*)(ws + off);  off += (size_t)8 * PH * 4;

    // ring (incl. zero-state slot + pad columns) and flags must start at zero
    hipMemsetAsync(Sring, 0, (size_t)8 * RING * SLAB * 2, stream);
    hipMemsetAsync(flags, 0, (size_t)8 * PH * 4, stream);

    prep_xs <<<(T_STEPS * B_SZ * XK + 255) / 256, 256, 0, stream>>>(xs, xs_pad);
    pack_w0 <<<(N0PAD * K0 + 255) / 256, 256, 0, stream>>>(Wih0, Whh0, Wc0);
    pack_w1 <<<(N1PAD * K1 + 255) / 256, 256, 0, stream>>>(Wih1, Whh1, Wc1);
    pack_bias<<<(N0PAD + 255) / 256, 256, 0, stream>>>(bih0, bhh0, b0, N0PAD);
    pack_bias<<<(N1PAD + 255) / 256, 256, 0, stream>>>(bih1, bhh1, b1, N1PAD);

    hipFuncSetAttribute((const void*)persist,
                        hipFuncAttributeMaxDynamicSharedMemorySize, 98304);
    void* args[] = { (void*)&xs_pad, (void*)&Wc0, (void*)&Wc1, (void*)&b0,
                     (void*)&b1, (void*)&Sring, (void*)&flags };
    hipLaunchCooperativeKernel((const void*)persist, dim3(256), dim3(256),
                               args, 98304, stream);

    classifier<<<B_SZ / 4, 256, 0, stream>>>(Sring, Wout, bout, out);
}

// Round 4
// 1711.255 us; speedup vs baseline: 2.1402x; 1.1545x over previous
//
#include <hip/hip_runtime.h>
#include <hip/hip_bf16.h>

#define T_STEPS 128
#define B_SZ    1024
#define IN_SZ   47
#define H_SZ    646
#define OUT_SZ  5

#define XK    96      // xs padded row stride (47 -> 96)
#define K0    768     // layer0 K = 96 + 672
#define K1    1344    // layer1 K = 672 + 672 (also the state-slab row stride)
#define N0PAD 704     // L0 cols padded (11 * 64)
#define N1PAD 672     // L1 cols padded (21 * 32)
#define RING  17      // state ring slots per row-group (fresh-address coherence)
#define SLAB  172032  // 128 rows * 1344 cols, elements per rg slab
#define PH    129     // phases: p=0..128

typedef __hip_bfloat16 bf16;
typedef unsigned short ush;
using frag8 = __attribute__((ext_vector_type(8))) short;  // 8 bf16
using f32x4 = __attribute__((ext_vector_type(4))) float;

// ---------------------------------------------------------------- prep kernels

__global__ void prep_xs(const float* __restrict__ xs, bf16* __restrict__ xs_pad) {
    int idx = blockIdx.x * blockDim.x + threadIdx.x;
    if (idx >= T_STEPS * B_SZ * XK) return;
    int k = idx % XK;
    int rb = idx / XK;
    float v = (k < IN_SZ) ? xs[(size_t)rb * IN_SZ + k] : 0.f;
    xs_pad[idx] = __float2bfloat16(v);
}

__global__ void pack_w0(const float* __restrict__ Wih, const float* __restrict__ Whh,
                        bf16* __restrict__ Wc) {
    int idx = blockIdx.x * blockDim.x + threadIdx.x;
    if (idx >= N0PAD * K0) return;
    int j = idx / K0, k = idx % K0;
    float v = 0.f;
    if (j < H_SZ) {
        if (k < IN_SZ)                      v = Wih[(size_t)j * IN_SZ + k];
        else if (k >= XK && k < XK + H_SZ)  v = Whh[(size_t)j * H_SZ + (k - XK)];
    }
    Wc[idx] = __float2bfloat16(v);
}

__global__ void pack_w1(const float* __restrict__ Wih, const float* __restrict__ Whh,
                        bf16* __restrict__ Wc) {
    int idx = blockIdx.x * blockDim.x + threadIdx.x;
    if (idx >= N1PAD * K1) return;
    int j = idx / K1, k = idx % K1;
    float v = 0.f;
    if (j < H_SZ) {
        if (k < H_SZ)                          v = Wih[(size_t)j * H_SZ + k];
        else if (k >= 672 && k < 672 + H_SZ)   v = Whh[(size_t)j * H_SZ + (k - 672)];
    }
    Wc[idx] = __float2bfloat16(v);
}

__global__ void pack_bias(const float* __restrict__ bi, const float* __restrict__ bh,
                          float* __restrict__ b, int n) {
    int j = blockIdx.x * blockDim.x + threadIdx.x;
    if (j >= n) return;
    b[j] = (j < H_SZ) ? (bi[j] + bh[j]) : 0.f;
}

// ---------------------------------------------------------------- persistent RNN
// 256 blocks x 512 threads (8 waves -> 2 waves/SIMD for latency hiding).
// bid&7 = row-group (128 rows), c8 = bid>>3:
//   c8 in [0,11): L0, 64-col tile, W0 slice (96 KB) pinned in LDS
//   c8 in [11,32): L1, 32-col tile, W1 slice (84 KB) pinned in LDS
// Each wave owns 16 rows (r=1); A-frags loaded global->reg with depth-4 ring.
// Phase p: L0 computes h0(p) (p<128); L1 computes h1(p-1) (p>=1).
// State in a per-rg ring of RING fresh slabs; producers use agent-scope
// stores, consumers plain loads + one agent-acquire fence per ring wrap.

__device__ __forceinline__ void tanh_store(ush* dst, float x) {
    x = fminf(fmaxf(x, -15.f), 15.f);
    float e = __expf(2.f * x);
    bf16 hb = __float2bfloat16((e - 1.f) / (e + 1.f));
    __hip_atomic_store(dst, *(ush*)&hb, __ATOMIC_RELAXED, __HIP_MEMORY_SCOPE_AGENT);
}

__global__ __launch_bounds__(512, 2) void persist(
    const bf16* __restrict__ xs_pad, const bf16* __restrict__ Wc0,
    const bf16* __restrict__ Wc1, const float* __restrict__ b0,
    const float* __restrict__ b1, bf16* __restrict__ Sring,
    int* __restrict__ flags)
{
    extern __shared__ ush Wlds[];
    const int bid  = blockIdx.x;
    const int rg   = bid & 7;
    const int c8   = bid >> 3;
    const bool isL0 = (c8 < 11);
    const int wv   = threadIdx.x >> 6;   // 0..7
    const int lane = threadIdx.x & 63;
    const int q8   = (lane >> 4) * 8;    // fragment k offset (elements)
    const int l15  = lane & 15;

    // ---- stage W slice into LDS in fragment order (once) ----
    if (isL0) {
        const int col0 = c8 * 64;
        for (int g = wv; g < 96; g += 8) {            // g = kc*4 + ct
            int kc = g >> 2, ct = g & 3;
            const bf16* src = Wc0 + (size_t)(col0 + ct*16 + l15) * K0 + kc*32 + q8;
            *(uint4*)&Wlds[g*512 + lane*8] = *(const uint4*)src;
        }
    } else {
        const int col0 = (c8 - 11) * 32;
        for (int g = wv; g < 84; g += 8) {            // g = kc*2 + ct
            int kc = g >> 1, ct = g & 1;
            const bf16* src = Wc1 + (size_t)(col0 + ct*16 + l15) * K1 + kc*32 + q8;
            *(uint4*)&Wlds[g*512 + lane*8] = *(const uint4*)src;
        }
    }
    __syncthreads();

    // hoisted per-thread constants
    float bias[4];
    int col0;
    if (isL0) {
        col0 = c8 * 64;
        #pragma unroll
        for (int ct = 0; ct < 4; ++ct) bias[ct] = b0[col0 + ct*16 + l15];
    } else {
        col0 = (c8 - 11) * 32;
        #pragma unroll
        for (int ct = 0; ct < 2; ++ct) bias[ct] = b1[col0 + ct*16 + l15];
    }
    const int loc = wv * 16 + l15;      // this wave's A-fragment row (16 rows/wave)
    bf16* const ringbase = Sring + (size_t)rg * RING * SLAB;
    int*  const flagbase = flags + rg * PH;

    for (int p = 0; p <= 128; ++p) {
        if (p > 0) {
            if (threadIdx.x == 0) {
                while (__hip_atomic_load(&flagbase[p-1], __ATOMIC_RELAXED,
                                         __HIP_MEMORY_SCOPE_AGENT) < 32)
                    __builtin_amdgcn_s_sleep(2);
            }
            __syncthreads();
            // ring wrap: recycled addresses may be stale in L1/L2 -> invalidate
            if (p >= RING + 1 && (p - 1) % RING == 0)
                __builtin_amdgcn_fence(__ATOMIC_ACQUIRE, "agent");
        }
        const bf16* rsl = ringbase + (size_t)((p + RING - 1) % RING) * SLAB;
        bf16*       wsl = ringbase + (size_t)(p % RING) * SLAB;
        const bool active = isL0 ? (p < 128) : (p >= 1);

        if (active) {
            if (isL0) {
                // A = [x_t(96) | h0(t-1)(672)], C = h0(t) -> slab cols [0,672)
                const bf16* xr = xs_pad + ((size_t)p * B_SZ + rg*128 + loc) * XK + q8;
                const bf16* hr = rsl + (size_t)loc * K1 + q8;
                f32x4 acc[4] = {};
                uint4 abuf[4];
                #pragma unroll
                for (int i = 0; i < 4; ++i)
                    abuf[i] = (i < 3) ? *(const uint4*)(xr + i*32)
                                      : *(const uint4*)(hr + (i-3)*32);
                #pragma unroll
                for (int kc = 0; kc < 24; ++kc) {
                    uint4 acur = abuf[kc & 3];
                    if (kc + 4 < 24) {
                        int kn = kc + 4;
                        abuf[kc & 3] = (kn < 3) ? *(const uint4*)(xr + kn*32)
                                                : *(const uint4*)(hr + (kn-3)*32);
                    }
                    frag8 af = *(const frag8*)&acur;
                    #pragma unroll
                    for (int ct = 0; ct < 4; ++ct) {
                        frag8 wf = *(const frag8*)&Wlds[(kc*4+ct)*512 + lane*8];
                        acc[ct] = __builtin_amdgcn_mfma_f32_16x16x32_bf16(
                            af, wf, acc[ct], 0, 0, 0);
                    }
                }
                const int rbase = wv*16 + (lane>>4)*4;
                #pragma unroll
                for (int ct = 0; ct < 4; ++ct) {
                    const int col = col0 + ct*16 + l15;
                    if (col < H_SZ) {
                        #pragma unroll
                        for (int i = 0; i < 4; ++i)
                            tanh_store((ush*)(wsl + (size_t)(rbase+i)*K1 + col),
                                       acc[ct][i] + bias[ct]);
                    }
                }
            } else {
                // A = slab row [h0(t-1) | h1(t-2)] (contiguous K=1344)
                // C = h1(t-1) -> slab cols [672, 1344)
                const bf16* ar = rsl + (size_t)loc * K1 + q8;
                f32x4 acc[2] = {};
                uint4 abuf[4];
                #pragma unroll
                for (int i = 0; i < 4; ++i) abuf[i] = *(const uint4*)(ar + i*32);
                #pragma unroll
                for (int kc = 0; kc < 42; ++kc) {
                    uint4 acur = abuf[kc & 3];
                    if (kc + 4 < 42)
                        abuf[kc & 3] = *(const uint4*)(ar + (kc+4)*32);
                    frag8 af = *(const frag8*)&acur;
                    #pragma unroll
                    for (int ct = 0; ct < 2; ++ct) {
                        frag8 wf = *(const frag8*)&Wlds[(kc*2+ct)*512 + lane*8];
                        acc[ct] = __builtin_amdgcn_mfma_f32_16x16x32_bf16(
                            af, wf, acc[ct], 0, 0, 0);
                    }
                }
                const int rbase = wv*16 + (lane>>4)*4;
                #pragma unroll
                for (int ct = 0; ct < 2; ++ct) {
                    const int col = col0 + ct*16 + l15;
                    if (col < H_SZ) {
                        #pragma unroll
                        for (int i = 0; i < 4; ++i)
                            tanh_store((ush*)(wsl + (size_t)(rbase+i)*K1 + 672 + col),
                                       acc[ct][i] + bias[ct]);
                    }
                }
            }
        }
        __syncthreads();   // all waves' stores drained before flagging
        if (threadIdx.x == 0)
            __hip_atomic_fetch_add(&flagbase[p], 1, __ATOMIC_RELAXED,
                                   __HIP_MEMORY_SCOPE_AGENT);
    }
}

// ---------------------------------------------------------------- classifier
__global__ __launch_bounds__(256) void classifier(
    const bf16* __restrict__ Sring, const float* __restrict__ Wout,
    const float* __restrict__ bout, float* __restrict__ out)
{
    const int wave = threadIdx.x >> 6, lane = threadIdx.x & 63;
    const int row = blockIdx.x * 4 + wave;
    const int rg = row >> 7, loc = row & 127;
    const bf16* h1 = Sring + ((size_t)rg * RING + (128 % RING)) * SLAB
                     + (size_t)loc * K1 + 672;
    float acc[OUT_SZ] = {0.f, 0.f, 0.f, 0.f, 0.f};
    for (int k = lane; k < H_SZ; k += 64) {
        float h = __bfloat162float(h1[k]);
        #pragma unroll
        for (int o = 0; o < OUT_SZ; ++o) acc[o] += h * Wout[(size_t)o * H_SZ + k];
    }
    #pragma unroll
    for (int o = 0; o < OUT_SZ; ++o) {
        float v = acc[o];
        #pragma unroll
        for (int off = 32; off; off >>= 1) v += __shfl_down(v, off, 64);
        if (lane == 0) out[(size_t)row * OUT_SZ + o] = v + bout[o];
    }
}

// ---------------------------------------------------------------- launch

extern "C" void kernel_launch(void* const* d_in, const int* in_sizes, int n_in,
                              void* d_out, int out_size, void* d_ws, size_t ws_size,
                              hipStream_t stream) {
    const float* xs   = (const float*)d_in[0];
    const float* Wih0 = (const float*)d_in[1];
    const float* Whh0 = (const float*)d_in[2];
    const float* bih0 = (const float*)d_in[3];
    const float* bhh0 = (const float*)d_in[4];
    const float* Wih1 = (const float*)d_in[5];
    const float* Whh1 = (const float*)d_in[6];
    const float* bih1 = (const float*)d_in[7];
    const float* bhh1 = (const float*)d_in[8];
    const float* Wout = (const float*)d_in[9];
    const float* bout = (const float*)d_in[10];
    float* out = (float*)d_out;

    char* ws = (char*)d_ws;
    size_t off = 0;
    bf16* xs_pad = (bf16*)(ws + off); off += (size_t)T_STEPS * B_SZ * XK * 2;
    bf16* Wc0    = (bf16*)(ws + off); off += (size_t)N0PAD * K0 * 2;
    bf16* Wc1    = (bf16*)(ws + off); off += (size_t)N1PAD * K1 * 2;
    float* b0    = (float*)(ws + off); off += (size_t)N0PAD * 4;
    float* b1    = (float*)(ws + off); off += (size_t)N1PAD * 4;
    bf16* Sring  = (bf16*)(ws + off); off += (size_t)8 * RING * SLAB * 2;
    int*  flags  = (int*)(ws + off);  off += (size_t)8 * PH * 4;

    // ring (incl. zero-state slot + pad columns) and flags must start at zero
    hipMemsetAsync(Sring, 0, (size_t)8 * RING * SLAB * 2, stream);
    hipMemsetAsync(flags, 0, (size_t)8 * PH * 4, stream);

    prep_xs <<<(T_STEPS * B_SZ * XK + 255) / 256, 256, 0, stream>>>(xs, xs_pad);
    pack_w0 <<<(N0PAD * K0 + 255) / 256, 256, 0, stream>>>(Wih0, Whh0, Wc0);
    pack_w1 <<<(N1PAD * K1 + 255) / 256, 256, 0, stream>>>(Wih1, Whh1, Wc1);
    pack_bias<<<(N0PAD + 255) / 256, 256, 0, stream>>>(bih0, bhh0, b0, N0PAD);
    pack_bias<<<(N1PAD + 255) / 256, 256, 0, stream>>>(bih1, bhh1, b1, N1PAD);

    hipFuncSetAttribute((const void*)persist,
                        hipFuncAttributeMaxDynamicSharedMemorySize, 98304);
    void* args[] = { (void*)&xs_pad, (void*)&Wc0, (void*)&Wc1, (void*)&b0,
                     (void*)&b1, (void*)&Sring, (void*)&flags };
    hipLaunchCooperativeKernel((const void*)persist, dim3(256), dim3(512),
                               args, 98304, stream);

    classifier<<<B_SZ / 4, 256, 0, stream>>>(Sring, Wout, bout, out);
}